// Round 3
// baseline (235.368 us; speedup 1.0000x reference)
//
#include <hip/hip_runtime.h>
#include <hip/hip_bf16.h>

// Problem constants
#define BB    16
#define CREF  256
#define CINC  256
#define COUTC 256
#define KKN   4
#define HH    56
#define WWW   56
#define HIDDEN 65
#define NPIX  3136          // 56*56
#define PPIX  3364          // 58*58 padded
#define TEMP  34.0f

typedef __bf16 bf16x8 __attribute__((ext_vector_type(8)));
typedef float  f32x4  __attribute__((ext_vector_type(4)));

// ---------------- ws layout (bytes) ----------------
#define WS_ATTN   0
#define WS_AGGB   4096
#define WS_POOL   24576
#define WS_AGGW   65536      // 16*9*8*256*32*2 = 18,874,368  [b][tap][cb8][cout][cin32] bf16
#define WS_XPAD   19005440   // 16*3364*256*2 = 27,557,888 (+slack for staging overread)

// ---------- 1. adaptive avg pool (one wave per (b,c)) + xpad border zeroing ----------
__global__ void pool_k(const float* __restrict__ ref, float* __restrict__ pooled,
                       __bf16* __restrict__ xpad) {
    int wid = threadIdx.x >> 6, lane = threadIdx.x & 63;
    int gw = blockIdx.x * 4 + wid;            // 0..4095 = b*256+c
    const float4* r4 = reinterpret_cast<const float4*>(ref) + (size_t)gw * 784;
    float s = 0.f;
    for (int i = lane; i < 784; i += 64) {
        float4 v = r4[i];
        s += v.x + v.y + v.z + v.w;
    }
    for (int o = 32; o; o >>= 1) s += __shfl_xor(s, o);
    if (lane == 0) pooled[gw] = s * (1.0f / (float)NPIX);

    // border zeroing: 16 b * 228 border positions = 3648 rows of 256 bf16 (512B)
    if (gw < 3648) {
        int b = gw / 228, i = gw % 228;
        int ph, pw;
        if (i < 58)       { ph = 0;        pw = i; }
        else if (i < 116) { ph = 57;       pw = i - 58; }
        else if (i < 172) { ph = i - 115;  pw = 0; }
        else              { ph = i - 171;  pw = 57; }
        uint2* dst = (uint2*)(xpad + ((size_t)b * PPIX + ph * 58 + pw) * 256);
        dst[lane] = (uint2){0u, 0u};
    }
}

// ---------- 2. attention (group-parallel fc1) + fused agg bias ----------
__global__ void attn_k(const float* __restrict__ pooled, const float* __restrict__ fc1w,
                       const float* __restrict__ fc2w, const float* __restrict__ fc2b,
                       const float* __restrict__ bias,
                       float* __restrict__ attn, float* __restrict__ aggb) {
    __shared__ float sp[BB * CREF];       // pooled copy
    __shared__ float sh[BB * HIDDEN];
    __shared__ float sl[BB * KKN];
    __shared__ float sa[BB * KKN];
    int t = threadIdx.x;
    for (int i = t; i < BB * CREF; i += 256) sp[i] = pooled[i];
    __syncthreads();
    // fc1: 16*65 = 1040 dot products, one per 16-lane group iteration
    int g = t >> 4, sub = t & 15;
    for (int d = g; d < BB * HIDDEN; d += 16) {
        int b = d / HIDDEN, j = d - b * HIDDEN;
        float s = 0.f;
        for (int c = sub; c < CREF; c += 16) s += sp[b * CREF + c] * fc1w[j * CREF + c];
        s += __shfl_xor(s, 1); s += __shfl_xor(s, 2);
        s += __shfl_xor(s, 4); s += __shfl_xor(s, 8);
        if (sub == 0) sh[d] = fmaxf(s, 0.f);
    }
    __syncthreads();
    if (t < BB * KKN) {
        int b = t >> 2, k = t & 3;
        float s = fc2b[k];
        for (int j = 0; j < HIDDEN; ++j) s += sh[b * HIDDEN + j] * fc2w[k * HIDDEN + j];
        sl[t] = s / TEMP;
    }
    __syncthreads();
    if (t < BB) {
        float m = -1e30f;
        for (int k = 0; k < KKN; ++k) m = fmaxf(m, sl[t * 4 + k]);
        float e[KKN], sum = 0.f;
        for (int k = 0; k < KKN; ++k) { e[k] = expf(sl[t * 4 + k] - m); sum += e[k]; }
        for (int k = 0; k < KKN; ++k) { sa[t * 4 + k] = e[k] / sum; attn[t * 4 + k] = e[k] / sum; }
    }
    __syncthreads();
    // agg bias: 16*256 outputs
    for (int p = t; p < BB * COUTC; p += 256) {
        int b = p >> 8, c = p & 255;
        float s = 0.f;
#pragma unroll
        for (int k = 0; k < KKN; ++k) s += sa[b * 4 + k] * bias[k * COUTC + c];
        aggb[p] = s;
    }
}

// ---------- 3. blend weights -> bf16 [b][tap][cb8][cout][cin32] ----------
// grid (32 cout-blocks, 8 cg), block 256 = (cout 8) x (cr 32)
__global__ void aggw_k(const float* __restrict__ attn, const float* __restrict__ weight,
                       __bf16* __restrict__ aggw) {
    __shared__ float s_attn[64];
    int t = threadIdx.x;
    int co = t >> 5, cr = t & 31;
    int cout = blockIdx.x * 8 + co;
    int cg = blockIdx.y;
    int cin = cg * 32 + cr;
    if (t < 64) s_attn[t] = attn[t];
    __syncthreads();
    float w[4][9];
#pragma unroll
    for (int k = 0; k < 4; ++k) {
        const float* wp = weight + ((size_t)(k * 256 + cout) * 256 + cin) * 9;
#pragma unroll
        for (int tp = 0; tp < 9; ++tp) w[k][tp] = wp[tp];
    }
    for (int b = 0; b < BB; ++b) {
        float a0 = s_attn[b * 4 + 0], a1 = s_attn[b * 4 + 1];
        float a2 = s_attn[b * 4 + 2], a3 = s_attn[b * 4 + 3];
#pragma unroll
        for (int tap = 0; tap < 9; ++tap) {
            float v = a0 * w[0][tap] + a1 * w[1][tap] + a2 * w[2][tap] + a3 * w[3][tap];
            aggw[(((size_t)((b * 9 + tap) * 8 + cg) * 256 + cout) * 32) + cr] = (__bf16)v;
        }
    }
}

// ---------- 4. x -> padded NHWC bf16 (interior, tiled transpose) ----------
__global__ void xpad_int_k(const float* __restrict__ x, __bf16* __restrict__ xpad) {
    __shared__ float tile[64][65];
    int pt = blockIdx.x;      // 0..48 pixel tile (64 px)
    int cg = blockIdx.y;      // 0..3 cin group (64 cins)
    int b  = blockIdx.z;
    int q = threadIdx.x >> 6, l = threadIdx.x & 63;
    for (int k = 0; k < 16; ++k) {
        int cl = q * 16 + k;
        tile[cl][l] = x[((size_t)(b * 256 + cg * 64 + cl)) * NPIX + pt * 64 + l];
    }
    __syncthreads();
    for (int k = 0; k < 16; ++k) {
        int pl = q * 16 + k;
        int pixel = pt * 64 + pl;
        int h = pixel / 56, w = pixel - h * 56;
        xpad[(((size_t)b * PPIX + (h + 1) * 58 + (w + 1)) * 256) + cg * 64 + l] =
            (__bf16)tile[l][pl];
    }
}

// ---------- 5. conv via implicit GEMM (MFMA bf16), 2-phase pipelined ----------
// block: 512 thr = 8 waves (2M x 4N) = 256 couts x 4 output rows (224 px).
// wave: 128 couts x 56 px (one row), Mr=8, Nr=4 (last frag 8 px waste).
// LDS: [cg(4)][row(6)][col(64)][16B] = 24KB per buffer, double-buffered.
// grid: flat 224 = b(16) x rp(14), XCD-swizzled so same-b blocks share an XCD L2.
__global__ __launch_bounds__(512, 2) void conv_k(const __bf16* __restrict__ xpad,
                                                 const __bf16* __restrict__ aggw,
                                                 const float* __restrict__ aggb,
                                                 float* __restrict__ out) {
    __shared__ __attribute__((aligned(16))) __bf16 lds[24608];   // 2 x 24KB + 64B pad
    const int orig = blockIdx.x;
    const int logical = (orig & 7) * 28 + (orig >> 3);   // bijective (224 % 8 == 0)
    const int b  = logical / 14;
    const int rp = logical - b * 14;                     // 0..13 row-quad
    const int tid = threadIdx.x;
    const int wid = tid >> 6, lane = tid & 63;
    const int l15 = lane & 15, l4 = lane >> 4;
    const int wm = wid & 1, wn = wid >> 1;               // wm: cout half, wn: row 0..3
    const int h0 = rp * 4;                               // padded top row staged

    // B-frag LDS byte offsets: [cg=l4][row=wn+kh][col=16nf+l15+kw][16B]
    int bo[4];
#pragma unroll
    for (int nf = 0; nf < 4; ++nf)
        bo[nf] = ((l4 * 6 + wn) * 64 + nf * 16 + l15) * 16;

    f32x4 acc[8][4];
#pragma unroll
    for (int m = 0; m < 8; ++m)
#pragma unroll
        for (int n = 0; n < 4; ++n) acc[m][n] = (f32x4){0.f, 0.f, 0.f, 0.f};

    const char* xb = (const char*)xpad + (size_t)b * PPIX * 512;

    // stage one 32-cin block (4 cg x 6 rows x 64 cols x 16B = 24KB): 3 loads/wave
    auto STAGE = [&](int buf, int cb8) {
#pragma unroll
        for (int j = 0; j < 3; ++j) {
            int k = wid * 3 + j;             // 0..23
            int cg = k / 6, row = k % 6;
            const char* src = xb + (size_t)((h0 + row) * 58 + lane) * 512 + cb8 * 64 + cg * 16;
            __builtin_amdgcn_global_load_lds(
                (const __attribute__((address_space(1))) void*)src,
                (__attribute__((address_space(3))) void*)((char*)lds + buf * 24576 + k * 1024),
                16, 0, 0);
        }
    };

    STAGE(0, 0);
    __syncthreads();
    int cur = 0;
    for (int cb8 = 0; cb8 < 8; ++cb8) {
        if (cb8 < 7) STAGE(cur ^ 1, cb8 + 1);
        const char* lb = (const char*)lds + cur * 24576;
        const __bf16* agb = aggw + ((size_t)(b * 9) * 8 + cb8) * 8192 + (wm * 128 + l15) * 32 + l4 * 8;
#pragma unroll
        for (int kh = 0; kh < 3; ++kh) {
#pragma unroll
            for (int kw = 0; kw < 3; ++kw) {
                const int tap = kh * 3 + kw;
                const __bf16* ap = agb + (size_t)tap * 65536;   // 8*8192 elems per tap
                bf16x8 a[8];
#pragma unroll
                for (int m = 0; m < 8; ++m) a[m] = *(const bf16x8*)(ap + m * 512);
#pragma unroll
                for (int nf = 0; nf < 4; ++nf) {
                    bf16x8 bb = *(const bf16x8*)(lb + bo[nf] + (kh * 64 + kw) * 16);
#pragma unroll
                    for (int m = 0; m < 8; ++m)
                        acc[m][nf] = __builtin_amdgcn_mfma_f32_16x16x32_bf16(a[m], bb, acc[m][nf], 0, 0, 0);
                }
            }
        }
        __syncthreads();
        cur ^= 1;
    }

    const int r = rp * 4 + wn;               // output row
#pragma unroll
    for (int m = 0; m < 8; ++m) {
#pragma unroll
        for (int i = 0; i < 4; ++i) {
            int cout = wm * 128 + m * 16 + l4 * 4 + i;
            float bv = aggb[b * COUTC + cout];
            float* op = out + ((size_t)(b * COUTC + cout) * NPIX + r * 56);
#pragma unroll
            for (int nf = 0; nf < 3; ++nf)
                __builtin_nontemporal_store(acc[m][nf][i] + bv, op + nf * 16 + l15);
            if (l15 < 8)
                __builtin_nontemporal_store(acc[m][3][i] + bv, op + 48 + l15);
        }
    }
}

extern "C" void kernel_launch(void* const* d_in, const int* in_sizes, int n_in,
                              void* d_out, int out_size, void* d_ws, size_t ws_size,
                              hipStream_t stream) {
    (void)in_sizes; (void)n_in; (void)out_size; (void)ws_size;
    const float* ref    = (const float*)d_in[0];
    const float* x      = (const float*)d_in[1];
    const float* fc1w   = (const float*)d_in[2];
    const float* fc2w   = (const float*)d_in[3];
    const float* fc2b   = (const float*)d_in[4];
    const float* weight = (const float*)d_in[5];
    const float* bias   = (const float*)d_in[6];
    float* out = (float*)d_out;
    char* ws = (char*)d_ws;

    float*  attn   = (float*)(ws + WS_ATTN);
    float*  aggb   = (float*)(ws + WS_AGGB);
    float*  pooled = (float*)(ws + WS_POOL);
    __bf16* aggw   = (__bf16*)(ws + WS_AGGW);
    __bf16* xpad   = (__bf16*)(ws + WS_XPAD);

    pool_k<<<1024, 256, 0, stream>>>(ref, pooled, xpad);
    attn_k<<<1, 256, 0, stream>>>(pooled, fc1w, fc2w, fc2b, bias, attn, aggb);
    aggw_k<<<dim3(32, 8), 256, 0, stream>>>(attn, weight, aggw);
    xpad_int_k<<<dim3(49, 4, 16), 256, 0, stream>>>(x, xpad);
    conv_k<<<224, 512, 0, stream>>>(xpad, aggw, aggb, out);
}

// Round 4
// 134.993 us; speedup vs baseline: 1.7436x; 1.7436x over previous
//
#include <hip/hip_runtime.h>
#include <hip/hip_bf16.h>

// Problem constants
#define BB    16
#define CREF  256
#define CINC  256
#define COUTC 256
#define KKN   4
#define HH    56
#define WWW   56
#define HIDDEN 65
#define NPIX  3136          // 56*56
#define PPIX  3364          // 58*58 padded
#define TEMP  34.0f

typedef __bf16 bf16x8 __attribute__((ext_vector_type(8)));
typedef float  f32x4  __attribute__((ext_vector_type(4)));

// ---------------- ws layout (bytes) ----------------
#define WS_ATTN   0
#define WS_AGGB   4096
#define WS_POOL   24576
#define WS_AGGW   65536      // 16*9*8*256*32*2 = 18,874,368  [b][tap][cb8][cout][cin32] bf16
#define WS_XPAD   19005440   // 16*3364*256*2 = 27,557,888 (+slack for staging overread)

// ---------- 1. adaptive avg pool (one wave per (b,c)) + xpad border zeroing ----------
__global__ void pool_k(const float* __restrict__ ref, float* __restrict__ pooled,
                       __bf16* __restrict__ xpad) {
    int wid = threadIdx.x >> 6, lane = threadIdx.x & 63;
    int gw = blockIdx.x * 4 + wid;            // 0..4095 = b*256+c
    const float4* r4 = reinterpret_cast<const float4*>(ref) + (size_t)gw * 784;
    float s = 0.f;
    for (int i = lane; i < 784; i += 64) {
        float4 v = r4[i];
        s += v.x + v.y + v.z + v.w;
    }
    for (int o = 32; o; o >>= 1) s += __shfl_xor(s, o);
    if (lane == 0) pooled[gw] = s * (1.0f / (float)NPIX);

    // border zeroing: 16 b * 228 border positions = 3648 rows of 256 bf16 (512B)
    if (gw < 3648) {
        int b = gw / 228, i = gw % 228;
        int ph, pw;
        if (i < 58)       { ph = 0;        pw = i; }
        else if (i < 116) { ph = 57;       pw = i - 58; }
        else if (i < 172) { ph = i - 115;  pw = 0; }
        else              { ph = i - 171;  pw = 57; }
        uint2* dst = (uint2*)(xpad + ((size_t)b * PPIX + ph * 58 + pw) * 256);
        dst[lane] = (uint2){0u, 0u};
    }
}

// ---------- 2. attention + agg bias: ONE BLOCK PER BATCH SAMPLE ----------
// fc1: thread t -> j = t>>2, quarter sub = t&3 (64 contiguous floats, 16 float4 loads, full ILP)
__global__ void attn_k(const float* __restrict__ pooled, const float* __restrict__ fc1w,
                       const float* __restrict__ fc2w, const float* __restrict__ fc2b,
                       const float* __restrict__ bias,
                       float* __restrict__ attn, float* __restrict__ aggb) {
    int b = blockIdx.x;
    int t = threadIdx.x;
    __shared__ float sh[HIDDEN + 7];
    __shared__ float sl[KKN];
    __shared__ float sa[KKN];
    const float* prow = pooled + b * CREF;
    {
        int j = t >> 2, sub = t & 3;
        const float4* w4 = (const float4*)(fc1w + j * CREF + sub * 64);
        const float4* p4 = (const float4*)(prow + sub * 64);
        float s = 0.f;
#pragma unroll
        for (int k = 0; k < 16; ++k) {
            float4 w = w4[k], p = p4[k];
            s += w.x * p.x + w.y * p.y + w.z * p.z + w.w * p.w;
        }
        s += __shfl_xor(s, 1); s += __shfl_xor(s, 2);
        if (sub == 0) sh[j] = fmaxf(s, 0.f);
    }
    if (t < 4) {   // j = 64
        const float4* w4 = (const float4*)(fc1w + 64 * CREF + t * 64);
        const float4* p4 = (const float4*)(prow + t * 64);
        float s = 0.f;
#pragma unroll
        for (int k = 0; k < 16; ++k) {
            float4 w = w4[k], p = p4[k];
            s += w.x * p.x + w.y * p.y + w.z * p.z + w.w * p.w;
        }
        s += __shfl_xor(s, 1); s += __shfl_xor(s, 2);
        if (t == 0) sh[64] = fmaxf(s, 0.f);
    }
    __syncthreads();
    if (t < KKN) {
        float s = fc2b[t];
        for (int j = 0; j < HIDDEN; ++j) s += sh[j] * fc2w[t * HIDDEN + j];
        sl[t] = s * (1.0f / TEMP);
    }
    __syncthreads();
    if (t == 0) {
        float m = fmaxf(fmaxf(sl[0], sl[1]), fmaxf(sl[2], sl[3]));
        float e0 = expf(sl[0] - m), e1 = expf(sl[1] - m);
        float e2 = expf(sl[2] - m), e3 = expf(sl[3] - m);
        float inv = 1.f / (e0 + e1 + e2 + e3);
        sa[0] = e0 * inv; sa[1] = e1 * inv; sa[2] = e2 * inv; sa[3] = e3 * inv;
        attn[b * 4 + 0] = sa[0]; attn[b * 4 + 1] = sa[1];
        attn[b * 4 + 2] = sa[2]; attn[b * 4 + 3] = sa[3];
    }
    __syncthreads();
    {
        float s = 0.f;
#pragma unroll
        for (int k = 0; k < KKN; ++k) s += sa[k] * bias[k * COUTC + t];
        aggb[b * COUTC + t] = s;
    }
}

// ---------- 3. blend weights -> bf16 [b][tap][cb8][cout][cin32] ----------
// grid (32 cout-blocks, 8 cg), block 256 = (cout 8) x (cr 32)
__global__ void aggw_k(const float* __restrict__ attn, const float* __restrict__ weight,
                       __bf16* __restrict__ aggw) {
    __shared__ float s_attn[64];
    int t = threadIdx.x;
    int co = t >> 5, cr = t & 31;
    int cout = blockIdx.x * 8 + co;
    int cg = blockIdx.y;
    int cin = cg * 32 + cr;
    if (t < 64) s_attn[t] = attn[t];
    __syncthreads();
    float w[4][9];
#pragma unroll
    for (int k = 0; k < 4; ++k) {
        const float* wp = weight + ((size_t)(k * 256 + cout) * 256 + cin) * 9;
#pragma unroll
        for (int tp = 0; tp < 9; ++tp) w[k][tp] = wp[tp];
    }
    for (int b = 0; b < BB; ++b) {
        float a0 = s_attn[b * 4 + 0], a1 = s_attn[b * 4 + 1];
        float a2 = s_attn[b * 4 + 2], a3 = s_attn[b * 4 + 3];
#pragma unroll
        for (int tap = 0; tap < 9; ++tap) {
            float v = a0 * w[0][tap] + a1 * w[1][tap] + a2 * w[2][tap] + a3 * w[3][tap];
            aggw[(((size_t)((b * 9 + tap) * 8 + cg) * 256 + cout) * 32) + cr] = (__bf16)v;
        }
    }
}

// ---------- 4. x -> padded NHWC bf16 (interior, tiled transpose) ----------
__global__ void xpad_int_k(const float* __restrict__ x, __bf16* __restrict__ xpad) {
    __shared__ float tile[64][65];
    int pt = blockIdx.x;      // 0..48 pixel tile (64 px)
    int cg = blockIdx.y;      // 0..3 cin group (64 cins)
    int b  = blockIdx.z;
    int q = threadIdx.x >> 6, l = threadIdx.x & 63;
    for (int k = 0; k < 16; ++k) {
        int cl = q * 16 + k;
        tile[cl][l] = x[((size_t)(b * 256 + cg * 64 + cl)) * NPIX + pt * 64 + l];
    }
    __syncthreads();
    for (int k = 0; k < 16; ++k) {
        int pl = q * 16 + k;
        int pixel = pt * 64 + pl;
        int h = pixel / 56, w = pixel - h * 56;
        xpad[(((size_t)b * PPIX + (h + 1) * 58 + (w + 1)) * 256) + cg * 64 + l] =
            (__bf16)tile[l][pl];
    }
}

// ---------- 5. conv via implicit GEMM (MFMA bf16), 2-phase pipelined ----------
// block: 512 thr = 8 waves (2M x 4N) = 256 couts x 4 output rows (224 px).
// wave: 128 couts x 56 px (one row), Mr=8, Nr=4 (last frag 8 px waste).
// LDS: [cg(4)][row(6)][col(64)][16B] = 24KB per buffer, double-buffered.
// grid: flat 224 = b(16) x rp(14), XCD-swizzled so same-b blocks share an XCD L2.
__global__ __launch_bounds__(512, 2) void conv_k(const __bf16* __restrict__ xpad,
                                                 const __bf16* __restrict__ aggw,
                                                 const float* __restrict__ aggb,
                                                 float* __restrict__ out) {
    __shared__ __attribute__((aligned(16))) __bf16 lds[24608];   // 2 x 24KB + 64B pad
    const int orig = blockIdx.x;
    const int logical = (orig & 7) * 28 + (orig >> 3);   // bijective (224 % 8 == 0)
    const int b  = logical / 14;
    const int rp = logical - b * 14;                     // 0..13 row-quad
    const int tid = threadIdx.x;
    const int wid = tid >> 6, lane = tid & 63;
    const int l15 = lane & 15, l4 = lane >> 4;
    const int wm = wid & 1, wn = wid >> 1;               // wm: cout half, wn: row 0..3
    const int h0 = rp * 4;                               // padded top row staged

    // B-frag LDS byte offsets: [cg=l4][row=wn+kh][col=16nf+l15+kw][16B]
    int bo[4];
#pragma unroll
    for (int nf = 0; nf < 4; ++nf)
        bo[nf] = ((l4 * 6 + wn) * 64 + nf * 16 + l15) * 16;

    f32x4 acc[8][4];
#pragma unroll
    for (int m = 0; m < 8; ++m)
#pragma unroll
        for (int n = 0; n < 4; ++n) acc[m][n] = (f32x4){0.f, 0.f, 0.f, 0.f};

    const char* xb = (const char*)xpad + (size_t)b * PPIX * 512;

    // stage one 32-cin block (4 cg x 6 rows x 64 cols x 16B = 24KB): 3 loads/wave
    auto STAGE = [&](int buf, int cb8) {
#pragma unroll
        for (int j = 0; j < 3; ++j) {
            int k = wid * 3 + j;             // 0..23
            int cg = k / 6, row = k % 6;
            const char* src = xb + (size_t)((h0 + row) * 58 + lane) * 512 + cb8 * 64 + cg * 16;
            __builtin_amdgcn_global_load_lds(
                (const __attribute__((address_space(1))) void*)src,
                (__attribute__((address_space(3))) void*)((char*)lds + buf * 24576 + k * 1024),
                16, 0, 0);
        }
    };

    STAGE(0, 0);
    __syncthreads();
    int cur = 0;
    for (int cb8 = 0; cb8 < 8; ++cb8) {
        if (cb8 < 7) STAGE(cur ^ 1, cb8 + 1);
        const char* lb = (const char*)lds + cur * 24576;
        const __bf16* agb = aggw + ((size_t)(b * 9) * 8 + cb8) * 8192 + (wm * 128 + l15) * 32 + l4 * 8;
#pragma unroll
        for (int kh = 0; kh < 3; ++kh) {
#pragma unroll
            for (int kw = 0; kw < 3; ++kw) {
                const int tap = kh * 3 + kw;
                const __bf16* ap = agb + (size_t)tap * 65536;   // 8*8192 elems per tap
                bf16x8 a[8];
#pragma unroll
                for (int m = 0; m < 8; ++m) a[m] = *(const bf16x8*)(ap + m * 512);
#pragma unroll
                for (int nf = 0; nf < 4; ++nf) {
                    bf16x8 bb = *(const bf16x8*)(lb + bo[nf] + (kh * 64 + kw) * 16);
#pragma unroll
                    for (int m = 0; m < 8; ++m)
                        acc[m][nf] = __builtin_amdgcn_mfma_f32_16x16x32_bf16(a[m], bb, acc[m][nf], 0, 0, 0);
                }
            }
        }
        __syncthreads();
        cur ^= 1;
    }

    const int r = rp * 4 + wn;               // output row
#pragma unroll
    for (int m = 0; m < 8; ++m) {
#pragma unroll
        for (int i = 0; i < 4; ++i) {
            int cout = wm * 128 + m * 16 + l4 * 4 + i;
            float bv = aggb[b * COUTC + cout];
            float* op = out + ((size_t)(b * COUTC + cout) * NPIX + r * 56);
#pragma unroll
            for (int nf = 0; nf < 3; ++nf)
                __builtin_nontemporal_store(acc[m][nf][i] + bv, op + nf * 16 + l15);
            if (l15 < 8)
                __builtin_nontemporal_store(acc[m][3][i] + bv, op + 48 + l15);
        }
    }
}

extern "C" void kernel_launch(void* const* d_in, const int* in_sizes, int n_in,
                              void* d_out, int out_size, void* d_ws, size_t ws_size,
                              hipStream_t stream) {
    (void)in_sizes; (void)n_in; (void)out_size; (void)ws_size;
    const float* ref    = (const float*)d_in[0];
    const float* x      = (const float*)d_in[1];
    const float* fc1w   = (const float*)d_in[2];
    const float* fc2w   = (const float*)d_in[3];
    const float* fc2b   = (const float*)d_in[4];
    const float* weight = (const float*)d_in[5];
    const float* bias   = (const float*)d_in[6];
    float* out = (float*)d_out;
    char* ws = (char*)d_ws;

    float*  attn   = (float*)(ws + WS_ATTN);
    float*  aggb   = (float*)(ws + WS_AGGB);
    float*  pooled = (float*)(ws + WS_POOL);
    __bf16* aggw   = (__bf16*)(ws + WS_AGGW);
    __bf16* xpad   = (__bf16*)(ws + WS_XPAD);

    pool_k<<<1024, 256, 0, stream>>>(ref, pooled, xpad);
    attn_k<<<16, 256, 0, stream>>>(pooled, fc1w, fc2w, fc2b, bias, attn, aggb);
    aggw_k<<<dim3(32, 8), 256, 0, stream>>>(attn, weight, aggw);
    xpad_int_k<<<dim3(49, 4, 16), 256, 0, stream>>>(x, xpad);
    conv_k<<<224, 512, 0, stream>>>(xpad, aggw, aggb, out);
}

// Round 5
// 127.534 us; speedup vs baseline: 1.8455x; 1.0585x over previous
//
#include <hip/hip_runtime.h>
#include <hip/hip_bf16.h>

// Problem constants
#define BB    16
#define CREF  256
#define CINC  256
#define COUTC 256
#define KKN   4
#define HH    56
#define WWW   56
#define HIDDEN 65
#define NPIX  3136          // 56*56
#define PPIX  3364          // 58*58 padded
#define TEMP  34.0f

typedef __bf16 bf16x8 __attribute__((ext_vector_type(8)));
typedef float  f32x4  __attribute__((ext_vector_type(4)));

// ---------------- ws layout (bytes) ----------------
#define WS_ATTN   0
#define WS_AGGB   4096
#define WS_POOL   24576
#define WS_AGGW   65536      // 16*2*8*36864 elems bf16 = 18,874,368 B  [b][ch][cb8][tap][cing][cout128][cin8]
#define WS_XPAD   19005440   // 16*3364*256*2 = 27,557,888 (+slack for staging overread)

// conv LDS sizing
#define XBUF  40960          // [cg4][row10][col64][16B]
#define ABUF  73728          // [tap9][cing4][cout128][16B]
#define LDS_TOT (2*XBUF + ABUF)   // 155,648 B

// ---------- 1. adaptive avg pool (one wave per (b,c)) + xpad border zeroing ----------
__global__ void pool_k(const float* __restrict__ ref, float* __restrict__ pooled,
                       __bf16* __restrict__ xpad) {
    int wid = threadIdx.x >> 6, lane = threadIdx.x & 63;
    int gw = blockIdx.x * 4 + wid;            // 0..4095 = b*256+c
    const float4* r4 = reinterpret_cast<const float4*>(ref) + (size_t)gw * 784;
    float s = 0.f;
    for (int i = lane; i < 784; i += 64) {
        float4 v = r4[i];
        s += v.x + v.y + v.z + v.w;
    }
    for (int o = 32; o; o >>= 1) s += __shfl_xor(s, o);
    if (lane == 0) pooled[gw] = s * (1.0f / (float)NPIX);

    // border zeroing: 16 b * 228 border positions, 512B rows
    if (gw < 3648) {
        int b = gw / 228, i = gw % 228;
        int ph, pw;
        if (i < 58)       { ph = 0;        pw = i; }
        else if (i < 116) { ph = 57;       pw = i - 58; }
        else if (i < 172) { ph = i - 115;  pw = 0; }
        else              { ph = i - 171;  pw = 57; }
        uint2* dst = (uint2*)(xpad + ((size_t)b * PPIX + ph * 58 + pw) * 256);
        dst[lane] = (uint2){0u, 0u};
    }
}

// ---------- 2. attention + agg bias: one block per batch sample ----------
__global__ void attn_k(const float* __restrict__ pooled, const float* __restrict__ fc1w,
                       const float* __restrict__ fc2w, const float* __restrict__ fc2b,
                       const float* __restrict__ bias,
                       float* __restrict__ attn, float* __restrict__ aggb) {
    int b = blockIdx.x;
    int t = threadIdx.x;
    __shared__ float sh[HIDDEN + 7];
    __shared__ float sl[KKN];
    __shared__ float sa[KKN];
    const float* prow = pooled + b * CREF;
    {
        int j = t >> 2, sub = t & 3;
        const float4* w4 = (const float4*)(fc1w + j * CREF + sub * 64);
        const float4* p4 = (const float4*)(prow + sub * 64);
        float s = 0.f;
#pragma unroll
        for (int k = 0; k < 16; ++k) {
            float4 w = w4[k], p = p4[k];
            s += w.x * p.x + w.y * p.y + w.z * p.z + w.w * p.w;
        }
        s += __shfl_xor(s, 1); s += __shfl_xor(s, 2);
        if (sub == 0) sh[j] = fmaxf(s, 0.f);
    }
    if (t < 4) {   // j = 64
        const float4* w4 = (const float4*)(fc1w + 64 * CREF + t * 64);
        const float4* p4 = (const float4*)(prow + t * 64);
        float s = 0.f;
#pragma unroll
        for (int k = 0; k < 16; ++k) {
            float4 w = w4[k], p = p4[k];
            s += w.x * p.x + w.y * p.y + w.z * p.z + w.w * p.w;
        }
        s += __shfl_xor(s, 1); s += __shfl_xor(s, 2);
        if (t == 0) sh[64] = fmaxf(s, 0.f);
    }
    __syncthreads();
    if (t < KKN) {
        float s = fc2b[t];
        for (int j = 0; j < HIDDEN; ++j) s += sh[j] * fc2w[t * HIDDEN + j];
        sl[t] = s * (1.0f / TEMP);
    }
    __syncthreads();
    if (t == 0) {
        float m = fmaxf(fmaxf(sl[0], sl[1]), fmaxf(sl[2], sl[3]));
        float e0 = expf(sl[0] - m), e1 = expf(sl[1] - m);
        float e2 = expf(sl[2] - m), e3 = expf(sl[3] - m);
        float inv = 1.f / (e0 + e1 + e2 + e3);
        sa[0] = e0 * inv; sa[1] = e1 * inv; sa[2] = e2 * inv; sa[3] = e3 * inv;
        attn[b * 4 + 0] = sa[0]; attn[b * 4 + 1] = sa[1];
        attn[b * 4 + 2] = sa[2]; attn[b * 4 + 3] = sa[3];
    }
    __syncthreads();
    {
        float s = 0.f;
#pragma unroll
        for (int k = 0; k < KKN; ++k) s += sa[k] * bias[k * COUTC + t];
        aggb[b * COUTC + t] = s;
    }
}

// ---------- 3. blend weights -> bf16 [b][ch][cb8][tap][cing][cout128][cin8] ----------
// grid (32 cout-blocks, 8 cb8), block 256 = (cout 8) x (cr 32)
__global__ void aggw_k(const float* __restrict__ attn, const float* __restrict__ weight,
                       __bf16* __restrict__ aggw) {
    __shared__ float s_attn[64];
    int t = threadIdx.x;
    int co = t >> 5, cr = t & 31;
    int cout = blockIdx.x * 8 + co;       // 0..255
    int cb8 = blockIdx.y;                 // 0..7
    int cin = cb8 * 32 + cr;
    if (t < 64) s_attn[t] = attn[t];
    __syncthreads();
    float w[4][9];
#pragma unroll
    for (int k = 0; k < 4; ++k) {
        const float* wp = weight + ((size_t)(k * 256 + cout) * 256 + cin) * 9;
#pragma unroll
        for (int tp = 0; tp < 9; ++tp) w[k][tp] = wp[tp];
    }
    int ch = cout >> 7, coutl = cout & 127;
    int cing = cr >> 3, cinr = cr & 7;
    for (int b = 0; b < BB; ++b) {
        float a0 = s_attn[b * 4 + 0], a1 = s_attn[b * 4 + 1];
        float a2 = s_attn[b * 4 + 2], a3 = s_attn[b * 4 + 3];
#pragma unroll
        for (int tap = 0; tap < 9; ++tap) {
            float v = a0 * w[0][tap] + a1 * w[1][tap] + a2 * w[2][tap] + a3 * w[3][tap];
            size_t e = (size_t)((b * 2 + ch) * 8 + cb8) * 36864 +
                       (tap * 4 + cing) * 1024 + coutl * 8 + cinr;
            aggw[e] = (__bf16)v;
        }
    }
}

// ---------- 4. x -> padded NHWC bf16 (interior, tiled transpose) ----------
__global__ void xpad_int_k(const float* __restrict__ x, __bf16* __restrict__ xpad) {
    __shared__ float tile[64][65];
    int pt = blockIdx.x;      // 0..48 pixel tile (64 px)
    int cg = blockIdx.y;      // 0..3 cin group (64 cins)
    int b  = blockIdx.z;
    int q = threadIdx.x >> 6, l = threadIdx.x & 63;
    for (int k = 0; k < 16; ++k) {
        int cl = q * 16 + k;
        tile[cl][l] = x[((size_t)(b * 256 + cg * 64 + cl)) * NPIX + pt * 64 + l];
    }
    __syncthreads();
    for (int k = 0; k < 16; ++k) {
        int pl = q * 16 + k;
        int pixel = pt * 64 + pl;
        int h = pixel / 56, w = pixel - h * 56;
        xpad[(((size_t)b * PPIX + (h + 1) * 58 + (w + 1)) * 256) + cg * 64 + l] =
            (__bf16)tile[l][pl];
    }
}

// ---------- 5. conv: implicit GEMM, A and X both LDS-staged ----------
// block: 128 couts x 8 output rows; 8 waves, wave = 128 couts x 1 row (Mr=8, Nr=4).
// LDS: X dbuf 2x40KB ([cg4][row10][col64][16B]) + A 73.7KB ([tap9][cing4][cout128][16B]).
// Per K-step (cb8): PhaseA taps0-3 (stage A-hi<-c, X<-c+1), barrier,
//                   PhaseB taps4-8 (stage A-lo<-c+1), barrier.
__global__ __launch_bounds__(512, 2) void conv_k(const __bf16* __restrict__ xpad,
                                                 const __bf16* __restrict__ aggw,
                                                 const float* __restrict__ aggb,
                                                 float* __restrict__ out) {
    extern __shared__ __attribute__((aligned(16))) char smem[];
    char* xs = smem;                 // 2 X buffers
    char* as = smem + 2 * XBUF;      // A buffer

    const int orig = blockIdx.x;
    const int logical = (orig & 7) * 28 + (orig >> 3);   // bijective, 224 = 8*28
    const int b  = logical / 14;
    const int r  = logical - b * 14;
    const int rp = r >> 1;            // 0..6 row-octet
    const int ch = r & 1;             // cout half
    const int tid = threadIdx.x;
    const int wid = tid >> 6, lane = tid & 63;
    const int l15 = lane & 15, l4 = lane >> 4;
    const int h0 = rp * 8;            // top padded row staged (rows h0..h0+9)

    const char* xb  = (const char*)xpad + (size_t)b * PPIX * 512;
    const char* awb = (const char*)aggw + (size_t)((b * 2 + ch) * 8) * ABUF;

    f32x4 acc[8][4];
#pragma unroll
    for (int m = 0; m < 8; ++m)
#pragma unroll
        for (int n = 0; n < 4; ++n) acc[m][n] = (f32x4){0.f, 0.f, 0.f, 0.f};

    // stage X K-block c into buffer buf: 40 x 1KB, 5 per wave
    auto XSTAGE = [&](int buf, int c) {
#pragma unroll
        for (int j = 0; j < 5; ++j) {
            int k = wid * 5 + j;             // 0..39
            int cg = k / 10, row = k - cg * 10;
            const char* src = xb + (size_t)((h0 + row) * 58 + lane) * 512 + c * 64 + cg * 16;
            __builtin_amdgcn_global_load_lds(
                (const __attribute__((address_space(1))) void*)src,
                (__attribute__((address_space(3))) void*)(xs + buf * XBUF + k * 1024),
                16, 0, 0);
        }
    };
    // stage A slots [k0, k0+8n) for K-block c (n loads per wave)
    auto ASTAGE = [&](int k0, int n, int c) {
        for (int j = 0; j < n; ++j) {
            int k = k0 + wid * n + j;
            const char* src = awb + (size_t)c * ABUF + k * 1024 + lane * 16;
            __builtin_amdgcn_global_load_lds(
                (const __attribute__((address_space(1))) void*)src,
                (__attribute__((address_space(3))) void*)(as + k * 1024),
                16, 0, 0);
        }
    };
    // compute taps [t0, t1) against X buffer buf
    auto COMPUTE = [&](int t0, int t1, int buf) {
        for (int t = t0; t < t1; ++t) {
            int kh = t / 3, kw = t - kh * 3;
            bf16x8 a[8];
#pragma unroll
            for (int m = 0; m < 8; ++m)
                a[m] = *(const bf16x8*)(as + (t * 4 + l4) * 2048 + (m * 16 + l15) * 16);
#pragma unroll
            for (int nf = 0; nf < 4; ++nf) {
                bf16x8 bb = *(const bf16x8*)(xs + buf * XBUF +
                    (((l4 * 10 + wid + kh) * 64) + nf * 16 + l15 + kw) * 16);
#pragma unroll
                for (int m = 0; m < 8; ++m)
                    acc[m][nf] = __builtin_amdgcn_mfma_f32_16x16x32_bf16(a[m], bb, acc[m][nf], 0, 0, 0);
            }
        }
    };

    // prologue: full X[0] + full A[0]
    XSTAGE(0, 0);
    { // 9 A loads per wave
        for (int j = 0; j < 9; ++j) {
            int k = wid * 9 + j;
            const char* src = awb + (size_t)0 * ABUF + k * 1024 + lane * 16;
            __builtin_amdgcn_global_load_lds(
                (const __attribute__((address_space(1))) void*)src,
                (__attribute__((address_space(3))) void*)(as + k * 1024),
                16, 0, 0);
        }
    }
    __syncthreads();

    int cur = 0;
    for (int c = 0; c < 8; ++c) {
        if (c > 0) ASTAGE(32, 5, c);          // A-hi <- c (consumed in PhaseB after barrier)
        if (c < 7) XSTAGE(cur ^ 1, c + 1);    // X <- c+1
        COMPUTE(0, 4, cur);                   // taps 0..3 (A slots 0..31)
        __syncthreads();
        if (c < 7) ASTAGE(0, 4, c + 1);       // A-lo <- c+1 (consumed next iter PhaseA)
        COMPUTE(4, 9, cur);                   // taps 4..8 (A slots 32..71)
        __syncthreads();
        cur ^= 1;
    }

    const int row = rp * 8 + wid;             // output row
#pragma unroll
    for (int m = 0; m < 8; ++m) {
#pragma unroll
        for (int i = 0; i < 4; ++i) {
            int cout = ch * 128 + m * 16 + l4 * 4 + i;
            float bv = aggb[b * COUTC + cout];
            float* op = out + ((size_t)(b * COUTC + cout) * NPIX + row * 56);
#pragma unroll
            for (int nf = 0; nf < 3; ++nf)
                __builtin_nontemporal_store(acc[m][nf][i] + bv, op + nf * 16 + l15);
            if (l15 < 8)
                __builtin_nontemporal_store(acc[m][3][i] + bv, op + 48 + l15);
        }
    }
}

extern "C" void kernel_launch(void* const* d_in, const int* in_sizes, int n_in,
                              void* d_out, int out_size, void* d_ws, size_t ws_size,
                              hipStream_t stream) {
    (void)in_sizes; (void)n_in; (void)out_size; (void)ws_size;
    const float* ref    = (const float*)d_in[0];
    const float* x      = (const float*)d_in[1];
    const float* fc1w   = (const float*)d_in[2];
    const float* fc2w   = (const float*)d_in[3];
    const float* fc2b   = (const float*)d_in[4];
    const float* weight = (const float*)d_in[5];
    const float* bias   = (const float*)d_in[6];
    float* out = (float*)d_out;
    char* ws = (char*)d_ws;

    float*  attn   = (float*)(ws + WS_ATTN);
    float*  aggb   = (float*)(ws + WS_AGGB);
    float*  pooled = (float*)(ws + WS_POOL);
    __bf16* aggw   = (__bf16*)(ws + WS_AGGW);
    __bf16* xpad   = (__bf16*)(ws + WS_XPAD);

    // allow >64KB dynamic LDS for conv_k (deterministic, capture-safe host call)
    hipFuncSetAttribute((const void*)conv_k,
                        hipFuncAttributeMaxDynamicSharedMemorySize, LDS_TOT);

    pool_k<<<1024, 256, 0, stream>>>(ref, pooled, xpad);
    attn_k<<<16, 256, 0, stream>>>(pooled, fc1w, fc2w, fc2b, bias, attn, aggb);
    aggw_k<<<dim3(32, 8), 256, 0, stream>>>(attn, weight, aggw);
    xpad_int_k<<<dim3(49, 4, 16), 256, 0, stream>>>(x, xpad);
    conv_k<<<224, 512, LDS_TOT, stream>>>(xpad, aggw, aggb, out);
}